// Round 3
// baseline (176.653 us; speedup 1.0000x reference)
//
#include <hip/hip_runtime.h>

// Loss = ||corr_norm(within1)-corr_norm(within2)||^2 + ||corr_norm(between1)-corr_norm(between2)||^2
// within_s  ∝ G1_s - 128*P2_s - 16384*m_s m_s^T   (G1 = X^T X over slice, bf16 MFMA, K=16384)
// between_s ∝ P2_s = rm^T rm (rm = xm - m, K=128)
// corr_norm is scale-invariant -> no 1/16384 anywhere.

typedef float f32x4 __attribute__((ext_vector_type(4)));
typedef short bf16x8 __attribute__((ext_vector_type(8)));
typedef unsigned short u16x8 __attribute__((ext_vector_type(8)));

// ---- ws layout (bytes) ----
static constexpr size_t OFF_RT    = 0;                         // bf16 R_T [2][768][16384]  = 50,331,648
static constexpr size_t OFF_XM    = 50331648;                  // f32 xm [2][128][768]      = 786,432
static constexpr size_t OFF_M     = 51118080;                  // f32 m  [2][768]           = 6,144
static constexpr size_t OFF_RM    = 51124224;                  // bf16 rm_T [2][768][128]   = 393,216
static constexpr size_t OFF_P1    = 51517440;                  // f32 [252][128*128]        = 16,515,072
static constexpr size_t OFF_P2    = 68032512;                  // f32 [42][128*128]         = 2,752,512
static constexpr size_t OFF_NORMS = 70785024;                  // f32 [4]
static constexpr size_t OFF_BPART = 70785280;                  // f32 [1344]

__device__ __forceinline__ unsigned short f2bf(float f) {
  union { float f; unsigned int u; } v; v.f = f;
  unsigned int u = v.u;
  unsigned int lsb = (u >> 16) & 1u;
  u += 0x7fffu + lsb;
  return (unsigned short)(u >> 16);
}

__device__ __forceinline__ void gload_lds16(const void* g, void* l) {
  __builtin_amdgcn_global_load_lds(
      (const __attribute__((address_space(1))) unsigned int*)g,
      (__attribute__((address_space(3))) unsigned int*)l, 16, 0, 0);
}

// ---------------- K1: per-batch column means + bf16 transpose-convert ----------------
// grid 256 (b_orig), block 192. Thread t owns cols d0=4t..4t+3.
__global__ void k1_means_convert(const float* __restrict__ x, float* __restrict__ xm,
                                 unsigned short* __restrict__ RT) {
  int borig = blockIdx.x, s = borig & 1, b = borig >> 1;
  int t = threadIdx.x;
  int d0 = t * 4;
  const float* xb = x + (size_t)borig * (128 * 768) + d0;
  unsigned short* rt = RT + (size_t)s * (768ull * 16384ull) + (size_t)d0 * 16384ull + (size_t)b * 128ull;
  float s0 = 0.f, s1 = 0.f, s2 = 0.f, s3 = 0.f;
  for (int n0 = 0; n0 < 128; n0 += 8) {
    f32x4 v[8];
#pragma unroll
    for (int j = 0; j < 8; ++j) v[j] = *reinterpret_cast<const f32x4*>(xb + (size_t)(n0 + j) * 768);
#pragma unroll
    for (int j = 0; j < 8; ++j) { s0 += v[j][0]; s1 += v[j][1]; s2 += v[j][2]; s3 += v[j][3]; }
#pragma unroll
    for (int i = 0; i < 4; ++i) {
      u16x8 w;
#pragma unroll
      for (int j = 0; j < 8; ++j) w[j] = f2bf(v[j][i]);
      *reinterpret_cast<u16x8*>(rt + (size_t)i * 16384ull + n0) = w;
    }
  }
  f32x4 mean; mean[0] = s0 * (1.f/128.f); mean[1] = s1 * (1.f/128.f);
  mean[2] = s2 * (1.f/128.f); mean[3] = s3 * (1.f/128.f);
  *reinterpret_cast<f32x4*>(xm + ((size_t)(s * 128 + b)) * 768ull + d0) = mean;
}

// ---------------- K2: slice mean + bf16 residual-mean transpose ----------------
// grid 2 (s), block 768 (d)
__global__ void k2_slice_mean(const float* __restrict__ xm, float* __restrict__ m,
                              unsigned short* __restrict__ rmT) {
  int s = blockIdx.x, d = threadIdx.x;
  const float* base = xm + (size_t)s * 128ull * 768ull + d;
  float acc = 0.f;
  for (int b = 0; b < 128; ++b) acc += base[(size_t)b * 768ull];
  float mv = acc * (1.f / 128.f);
  m[s * 768 + d] = mv;
  unsigned short* rt = rmT + ((size_t)s * 768ull + d) * 128ull;
  for (int b = 0; b < 128; ++b) rt[b] = f2bf(base[(size_t)b * 768ull] - mv);
}

// ---------------- K3: C = A^T A tile GEMM (bf16 MFMA), triangle tiles, split-K ----------------
__device__ __forceinline__ void stage_tile(const unsigned short* __restrict__ g, int KP, int k0,
                                           unsigned short* lds, int wave, int lane) {
#pragma unroll
  for (int i = 0; i < 4; ++i) {
    int cb = (i * 4 + wave) * 64;       // wave-uniform chunk base
    int chunk = cb + lane;
    int r = chunk >> 3, sl = chunk & 7;
    int ss = sl ^ (r & 7);              // inverse-swizzled global source
    const unsigned short* src = g + (size_t)r * KP + (k0 + ss * 8);
    gload_lds16(src, lds + (size_t)cb * 8);
  }
}

__device__ __forceinline__ bf16x8 read_frag(const unsigned short* lds, int row, int slot) {
  int chunk = row * 8 + (slot ^ (row & 7));   // swizzled read
  return *reinterpret_cast<const bf16x8*>(lds + chunk * 8);
}

__device__ __forceinline__ void tp2tile(int tp, int& td, int& te) {
  td = 0; int t2 = tp;
  while (t2 >= 6 - td) { t2 -= 6 - td; ++td; }
  te = td + t2;
}

__global__ void __launch_bounds__(256) gemm_ata(const unsigned short* __restrict__ R,
                                                size_t slice_stride, int KP,
                                                float* __restrict__ P, int ksplit, int tot_steps) {
  __shared__ unsigned short Ta[128 * 64];
  __shared__ unsigned short Tb[128 * 64];
  int bid = blockIdx.x;
  int c = bid % ksplit; int rest = bid / ksplit;
  int s = rest & 1; int tp = rest >> 1;
  int td, te; tp2tile(tp, td, te);
  int step0 = (tot_steps * c) / ksplit, step1 = (tot_steps * (c + 1)) / ksplit;
  const unsigned short* Ra = R + (size_t)s * slice_stride + (size_t)(td * 128) * KP;
  const unsigned short* Rb = R + (size_t)s * slice_stride + (size_t)(te * 128) * KP;
  int tid = threadIdx.x, wave = tid >> 6, lane = tid & 63;
  int m_off = (wave >> 1) * 64, n_off = (wave & 1) * 64;
  int row_a = m_off + (lane & 15), row_b = n_off + (lane & 15);
  f32x4 acc[4][4];
#pragma unroll
  for (int i = 0; i < 4; ++i)
#pragma unroll
    for (int j = 0; j < 4; ++j) { acc[i][j][0]=0.f; acc[i][j][1]=0.f; acc[i][j][2]=0.f; acc[i][j][3]=0.f; }

  for (int kt = step0; kt < step1; ++kt) {
    int k0 = kt * 64;
    __syncthreads();
    stage_tile(Ra, KP, k0, Ta, wave, lane);
    stage_tile(Rb, KP, k0, Tb, wave, lane);
    __syncthreads();
#pragma unroll
    for (int ks = 0; ks < 2; ++ks) {
      bf16x8 a[4], b[4];
      int slot = ks * 4 + (lane >> 4);
#pragma unroll
      for (int mi = 0; mi < 4; ++mi) a[mi] = read_frag(Ta, row_a + mi * 16, slot);
#pragma unroll
      for (int ni = 0; ni < 4; ++ni) b[ni] = read_frag(Tb, row_b + ni * 16, slot);
#pragma unroll
      for (int mi = 0; mi < 4; ++mi)
#pragma unroll
        for (int ni = 0; ni < 4; ++ni)
          acc[mi][ni] = __builtin_amdgcn_mfma_f32_16x16x32_bf16(a[mi], b[ni], acc[mi][ni], 0, 0, 0);
    }
  }
  float* pout = P + (size_t)bid * (128 * 128);
  int hi = lane >> 4, lo = lane & 15;
#pragma unroll
  for (int mi = 0; mi < 4; ++mi)
#pragma unroll
    for (int ni = 0; ni < 4; ++ni)
#pragma unroll
      for (int r = 0; r < 4; ++r) {
        int rr = m_off + mi * 16 + hi * 4 + r;
        int cc = n_off + ni * 16 + lo;
        pout[rr * 128 + cc] = acc[mi][ni][r];
      }
}

// ---------------- reduction helper ----------------
__device__ __forceinline__ float block_reduce(float v, float* lds, int nwaves) {
  int lane = threadIdx.x & 63, w = threadIdx.x >> 6;
#pragma unroll
  for (int off = 32; off; off >>= 1) v += __shfl_down(v, off, 64);
  if (lane == 0) lds[w] = v;
  __syncthreads();
  float r = 0.f;
  if (threadIdx.x == 0) for (int i = 0; i < nwaves; ++i) r += lds[i];
  __syncthreads();
  return r;  // valid on thread 0
}

// ---------------- K4: diag norms ----------------
__global__ void k4_norms(const float* __restrict__ P1, const float* __restrict__ P2,
                         const float* __restrict__ m, float* __restrict__ norms) {
  __shared__ float red[12];
  int d = threadIdx.x;  // 768
  int td = d >> 7, r = d & 127;
  int tpd = td * 6 - (td * (td - 1)) / 2;   // diagonal tile index
  float vals[4];
  for (int s = 0; s < 2; ++s) {
    float g1 = 0.f;
    const float* b1 = P1 + (size_t)((tpd * 2 + s) * 6) * 16384ull + r * 129;
    for (int c6 = 0; c6 < 6; ++c6) g1 += b1[(size_t)c6 * 16384ull];
    float p2v = P2[(size_t)(tpd * 2 + s) * 16384ull + r * 129];
    float mv = m[s * 768 + d];
    float wd = g1 - 128.0f * p2v - 16384.0f * mv * mv;
    vals[0 + s] = wd * wd;
    vals[2 + s] = p2v * p2v;
  }
  for (int i = 0; i < 4; ++i) {
    float tot = block_reduce(vals[i], red, 12);
    if (threadIdx.x == 0) norms[i] = sqrtf(tot);
    __syncthreads();
  }
}

// ---------------- K5: elementwise squared diffs (triangle-weighted) ----------------
__global__ void k5_elem(const float* __restrict__ P1, const float* __restrict__ P2,
                        const float* __restrict__ m, const float* __restrict__ norms,
                        float* __restrict__ bpart) {
  __shared__ float red[4];
  int bid = blockIdx.x;
  int tp = bid >> 6;
  int td, te; tp2tile(tp, td, te);
  int idx = ((bid & 63) << 8) + threadIdx.x;  // 0..16383 within tile
  int r = idx >> 7, cc = idx & 127;
  int d = td * 128 + r, e = te * 128 + cc;
  float w[2], bt[2];
  for (int s = 0; s < 2; ++s) {
    const float* base1 = P1 + (size_t)((tp * 2 + s) * 6) * 16384ull + idx;
    float g1 = 0.f;
    for (int c6 = 0; c6 < 6; ++c6) g1 += base1[(size_t)c6 * 16384ull];
    float p2v = P2[(size_t)(tp * 2 + s) * 16384ull + idx];
    float W = g1 - 128.0f * p2v - 16384.0f * m[s * 768 + d] * m[s * 768 + e];
    w[s] = W / norms[s];
    bt[s] = p2v / norms[2 + s];
  }
  float dw = w[0] - w[1], db = bt[0] - bt[1];
  float contrib = dw * dw + db * db;
  if (td != te) contrib *= 2.0f;
  float tot = block_reduce(contrib, red, 4);
  if (threadIdx.x == 0) bpart[bid] = tot;
}

// ---------------- K6: final sum ----------------
__global__ void k6_final(const float* __restrict__ bpart, float* __restrict__ out) {
  __shared__ float red[4];
  float v = 0.f;
  for (int i = threadIdx.x; i < 1344; i += 256) v += bpart[i];
  float tot = block_reduce(v, red, 4);
  if (threadIdx.x == 0) out[0] = tot;
}

extern "C" void kernel_launch(void* const* d_in, const int* in_sizes, int n_in,
                              void* d_out, int out_size, void* d_ws, size_t ws_size,
                              hipStream_t stream) {
  const float* x = (const float*)d_in[0];
  char* ws = (char*)d_ws;
  unsigned short* RT  = (unsigned short*)(ws + OFF_RT);
  float* xm           = (float*)(ws + OFF_XM);
  float* m            = (float*)(ws + OFF_M);
  unsigned short* rmT = (unsigned short*)(ws + OFF_RM);
  float* P1           = (float*)(ws + OFF_P1);
  float* P2           = (float*)(ws + OFF_P2);
  float* norms        = (float*)(ws + OFF_NORMS);
  float* bpart        = (float*)(ws + OFF_BPART);
  float* out          = (float*)d_out;

  hipLaunchKernelGGL(k1_means_convert, dim3(256), dim3(192), 0, stream, x, xm, RT);
  hipLaunchKernelGGL(k2_slice_mean, dim3(2), dim3(768), 0, stream, xm, m, rmT);
  // big GEMM: 21 triangle tiles x 2 slices x ksplit 6 = 252 blocks, K=16384 (256 BK-steps)
  hipLaunchKernelGGL(gemm_ata, dim3(252), dim3(256), 0, stream,
                     RT, (size_t)(768ull * 16384ull), 16384, P1, 6, 256);
  // between GEMM: K=128 (2 BK-steps), 42 blocks
  hipLaunchKernelGGL(gemm_ata, dim3(42), dim3(256), 0, stream,
                     rmT, (size_t)(768ull * 128ull), 128, P2, 1, 2);
  hipLaunchKernelGGL(k4_norms, dim3(1), dim3(768), 0, stream, P1, P2, m, norms);
  hipLaunchKernelGGL(k5_elem, dim3(1344), dim3(256), 0, stream, P1, P2, m, norms, bpart);
  hipLaunchKernelGGL(k6_final, dim3(1), dim3(256), 0, stream, bpart, out);
}

// Round 5
// 161.743 us; speedup vs baseline: 1.0922x; 1.0922x over previous
//
#include <hip/hip_runtime.h>

// Loss = ||corr_norm(within1)-corr_norm(within2)||^2 + ||corr_norm(between1)-corr_norm(between2)||^2
// within_s  ∝ G1_s - 128*P2_s - 16384*m_s m_s^T   (G1 = X^T X over slice, bf16 MFMA, K=16384)
// between_s ∝ P2_s = rm^T rm (rm = xm - m, K=128)
// corr_norm is scale-invariant -> no 1/16384 anywhere.

typedef float f32x4 __attribute__((ext_vector_type(4)));
typedef short bf16x8 __attribute__((ext_vector_type(8)));

// ---- ws layout (bytes) ----
static constexpr size_t OFF_RT    = 0;                         // bf16 R_T [2][768][16384]  = 50,331,648
static constexpr size_t OFF_XM    = 50331648;                  // f32 xm [2][128][768]      = 786,432
static constexpr size_t OFF_M     = 51118080;                  // f32 m  [2][768]           = 6,144
static constexpr size_t OFF_RM    = 51124224;                  // bf16 rm_T [2][768][128]   = 393,216
static constexpr size_t OFF_P1    = 51517440;                  // f32 [252][128*128]        = 16,515,072
static constexpr size_t OFF_P2    = 68032512;                  // f32 [42][128*128]         = 2,752,512
static constexpr size_t OFF_NORMS = 70785024;                  // f32 [4]
static constexpr size_t OFF_BPART = 70785280;                  // f32 [1344]

__device__ __forceinline__ unsigned int f2bf_u32(float f) {
  union { float f; unsigned int u; } v; v.f = f;
  unsigned int u = v.u;
  unsigned int lsb = (u >> 16) & 1u;
  u += 0x7fffu + lsb;
  return u >> 16;
}

__device__ __forceinline__ void gload_lds16(const void* g, void* l) {
  __builtin_amdgcn_global_load_lds(
      (const __attribute__((address_space(1))) unsigned int*)g,
      (__attribute__((address_space(3))) unsigned int*)l, 16, 0, 0);
}

// ---------------- K1 v2: register-blocked transpose-convert + column means ----------------
// grid 6144 = 128 (s,b-pair) x 48 dgroups; block 256 = 4 waves.
// Wave w owns d0 = dg*16 + w*4 (block covers a full 64B line span of 16 floats).
// Lane l: half = l>>5 -> b = bp*2 + half; n0 = (l&31)*4. Loads 4x4 f32 block,
// register-transposes to 4 strips [d][4n] (8B), stores with wave-uniform d:
// 64 lanes -> 512B contiguous per store instr (write amplification 1x).
__global__ void __launch_bounds__(256) k1_means_convert(const float* __restrict__ x,
                                                        float* __restrict__ xm,
                                                        unsigned short* __restrict__ RT) {
  int bid = blockIdx.x;
  int dg = bid % 48, pair = bid / 48;
  int s = pair >> 6, bp = pair & 63;
  int tid = threadIdx.x, w = tid >> 6, lane = tid & 63;
  int half = lane >> 5;
  int b = bp * 2 + half;            // half-batch index within slice s
  int borig = (b << 1) | s;         // original batch index
  int n0 = (lane & 31) * 4;
  int d0 = dg * 16 + w * 4;

  const float* src = x + (size_t)borig * (128 * 768) + (size_t)n0 * 768 + d0;
  f32x4 v0 = *reinterpret_cast<const f32x4*>(src);
  f32x4 v1 = *reinterpret_cast<const f32x4*>(src + 768);
  f32x4 v2 = *reinterpret_cast<const f32x4*>(src + 1536);
  f32x4 v3 = *reinterpret_cast<const f32x4*>(src + 2304);

  unsigned short* dstbase = RT + (size_t)s * (768ull * 16384ull)
                               + (size_t)d0 * 16384ull + (size_t)(b * 128 + n0);
  float colsum[4];
#pragma unroll
  for (int j = 0; j < 4; ++j) {
    uint2 st;
    st.x = f2bf_u32(v0[j]) | (f2bf_u32(v1[j]) << 16);
    st.y = f2bf_u32(v2[j]) | (f2bf_u32(v3[j]) << 16);
    *reinterpret_cast<uint2*>(dstbase + (size_t)j * 16384ull) = st;
    colsum[j] = v0[j] + v1[j] + v2[j] + v3[j];
  }
  // reduce over the 32 lanes of each half (sum over n=0..127 for this b)
#pragma unroll
  for (int off = 16; off; off >>= 1) {
#pragma unroll
    for (int j = 0; j < 4; ++j) colsum[j] += __shfl_xor(colsum[j], off, 64);
  }
  if ((lane & 31) == 0) {
    f32x4 mean;
#pragma unroll
    for (int j = 0; j < 4; ++j) mean[j] = colsum[j] * (1.f / 128.f);
    *reinterpret_cast<f32x4*>(xm + ((size_t)(s * 128 + b)) * 768ull + d0) = mean;
  }
}

// ---------------- K2: slice mean + bf16 residual-mean transpose ----------------
// grid 2 (s), block 768 (d)
__global__ void k2_slice_mean(const float* __restrict__ xm, float* __restrict__ m,
                              unsigned short* __restrict__ rmT) {
  int s = blockIdx.x, d = threadIdx.x;
  const float* base = xm + (size_t)s * 128ull * 768ull + d;
  float acc = 0.f;
  for (int b = 0; b < 128; ++b) acc += base[(size_t)b * 768ull];
  float mv = acc * (1.f / 128.f);
  m[s * 768 + d] = mv;
  unsigned short* rt = rmT + ((size_t)s * 768ull + d) * 128ull;
  for (int b = 0; b < 128; ++b) rt[b] = (unsigned short)f2bf_u32(base[(size_t)b * 768ull] - mv);
}

// ---------------- K3: C = A^T A tile GEMM (bf16 MFMA), triangle tiles, split-K ----------------
__device__ __forceinline__ void stage_tile(const unsigned short* __restrict__ g, int KP, int k0,
                                           unsigned short* lds, int wave, int lane) {
#pragma unroll
  for (int i = 0; i < 4; ++i) {
    int cb = (i * 4 + wave) * 64;       // wave-uniform chunk base
    int chunk = cb + lane;
    int r = chunk >> 3, sl = chunk & 7;
    int ss = sl ^ (r & 7);              // inverse-swizzled global source
    const unsigned short* src = g + (size_t)r * KP + (k0 + ss * 8);
    gload_lds16(src, lds + (size_t)cb * 8);
  }
}

__device__ __forceinline__ bf16x8 read_frag(const unsigned short* lds, int row, int slot) {
  int chunk = row * 8 + (slot ^ (row & 7));   // swizzled read
  return *reinterpret_cast<const bf16x8*>(lds + chunk * 8);
}

__device__ __forceinline__ void tp2tile(int tp, int& td, int& te) {
  td = 0; int t2 = tp;
  while (t2 >= 6 - td) { t2 -= 6 - td; ++td; }
  te = td + t2;
}

__global__ void __launch_bounds__(256) gemm_ata(const unsigned short* __restrict__ R,
                                                size_t slice_stride, int KP,
                                                float* __restrict__ P, int ksplit, int tot_steps) {
  __shared__ unsigned short Ta[128 * 64];
  __shared__ unsigned short Tb[128 * 64];
  int bid = blockIdx.x;
  int c = bid % ksplit; int rest = bid / ksplit;
  int s = rest & 1; int tp = rest >> 1;
  int td, te; tp2tile(tp, td, te);
  int step0 = (tot_steps * c) / ksplit, step1 = (tot_steps * (c + 1)) / ksplit;
  const unsigned short* Ra = R + (size_t)s * slice_stride + (size_t)(td * 128) * KP;
  const unsigned short* Rb = R + (size_t)s * slice_stride + (size_t)(te * 128) * KP;
  int tid = threadIdx.x, wave = tid >> 6, lane = tid & 63;
  int m_off = (wave >> 1) * 64, n_off = (wave & 1) * 64;
  int row_a = m_off + (lane & 15), row_b = n_off + (lane & 15);
  f32x4 acc[4][4];
#pragma unroll
  for (int i = 0; i < 4; ++i)
#pragma unroll
    for (int j = 0; j < 4; ++j) { acc[i][j][0]=0.f; acc[i][j][1]=0.f; acc[i][j][2]=0.f; acc[i][j][3]=0.f; }

  for (int kt = step0; kt < step1; ++kt) {
    int k0 = kt * 64;
    __syncthreads();
    stage_tile(Ra, KP, k0, Ta, wave, lane);
    stage_tile(Rb, KP, k0, Tb, wave, lane);
    __syncthreads();
#pragma unroll
    for (int ks = 0; ks < 2; ++ks) {
      bf16x8 a[4], b[4];
      int slot = ks * 4 + (lane >> 4);
#pragma unroll
      for (int mi = 0; mi < 4; ++mi) a[mi] = read_frag(Ta, row_a + mi * 16, slot);
#pragma unroll
      for (int ni = 0; ni < 4; ++ni) b[ni] = read_frag(Tb, row_b + ni * 16, slot);
#pragma unroll
      for (int mi = 0; mi < 4; ++mi)
#pragma unroll
        for (int ni = 0; ni < 4; ++ni)
          acc[mi][ni] = __builtin_amdgcn_mfma_f32_16x16x32_bf16(a[mi], b[ni], acc[mi][ni], 0, 0, 0);
    }
  }
  float* pout = P + (size_t)bid * (128 * 128);
  int hi = lane >> 4, lo = lane & 15;
#pragma unroll
  for (int mi = 0; mi < 4; ++mi)
#pragma unroll
    for (int ni = 0; ni < 4; ++ni)
#pragma unroll
      for (int r = 0; r < 4; ++r) {
        int rr = m_off + mi * 16 + hi * 4 + r;
        int cc = n_off + ni * 16 + lo;
        pout[rr * 128 + cc] = acc[mi][ni][r];
      }
}

// ---------------- reduction helper ----------------
__device__ __forceinline__ float block_reduce(float v, float* lds, int nwaves) {
  int lane = threadIdx.x & 63, w = threadIdx.x >> 6;
#pragma unroll
  for (int off = 32; off; off >>= 1) v += __shfl_down(v, off, 64);
  if (lane == 0) lds[w] = v;
  __syncthreads();
  float r = 0.f;
  if (threadIdx.x == 0) for (int i = 0; i < nwaves; ++i) r += lds[i];
  __syncthreads();
  return r;  // valid on thread 0
}

// ---------------- K4: diag norms ----------------
__global__ void k4_norms(const float* __restrict__ P1, const float* __restrict__ P2,
                         const float* __restrict__ m, float* __restrict__ norms) {
  __shared__ float red[12];
  int d = threadIdx.x;  // 768
  int td = d >> 7, r = d & 127;
  int tpd = td * 6 - (td * (td - 1)) / 2;   // diagonal tile index
  float vals[4];
  for (int s = 0; s < 2; ++s) {
    float g1 = 0.f;
    const float* b1 = P1 + (size_t)((tpd * 2 + s) * 6) * 16384ull + r * 129;
    for (int c6 = 0; c6 < 6; ++c6) g1 += b1[(size_t)c6 * 16384ull];
    float p2v = P2[(size_t)(tpd * 2 + s) * 16384ull + r * 129];
    float mv = m[s * 768 + d];
    float wd = g1 - 128.0f * p2v - 16384.0f * mv * mv;
    vals[0 + s] = wd * wd;
    vals[2 + s] = p2v * p2v;
  }
  for (int i = 0; i < 4; ++i) {
    float tot = block_reduce(vals[i], red, 12);
    if (threadIdx.x == 0) norms[i] = sqrtf(tot);
    __syncthreads();
  }
}

// ---------------- K5: elementwise squared diffs (triangle-weighted) ----------------
__global__ void k5_elem(const float* __restrict__ P1, const float* __restrict__ P2,
                        const float* __restrict__ m, const float* __restrict__ norms,
                        float* __restrict__ bpart) {
  __shared__ float red[4];
  int bid = blockIdx.x;
  int tp = bid >> 6;
  int td, te; tp2tile(tp, td, te);
  int idx = ((bid & 63) << 8) + threadIdx.x;  // 0..16383 within tile
  int r = idx >> 7, cc = idx & 127;
  int d = td * 128 + r, e = te * 128 + cc;
  float w[2], bt[2];
  for (int s = 0; s < 2; ++s) {
    const float* base1 = P1 + (size_t)((tp * 2 + s) * 6) * 16384ull + idx;
    float g1 = 0.f;
    for (int c6 = 0; c6 < 6; ++c6) g1 += base1[(size_t)c6 * 16384ull];
    float p2v = P2[(size_t)(tp * 2 + s) * 16384ull + idx];
    float W = g1 - 128.0f * p2v - 16384.0f * m[s * 768 + d] * m[s * 768 + e];
    w[s] = W / norms[s];
    bt[s] = p2v / norms[2 + s];
  }
  float dw = w[0] - w[1], db = bt[0] - bt[1];
  float contrib = dw * dw + db * db;
  if (td != te) contrib *= 2.0f;
  float tot = block_reduce(contrib, red, 4);
  if (threadIdx.x == 0) bpart[bid] = tot;
}

// ---------------- K6: final sum ----------------
__global__ void k6_final(const float* __restrict__ bpart, float* __restrict__ out) {
  __shared__ float red[4];
  float v = 0.f;
  for (int i = threadIdx.x; i < 1344; i += 256) v += bpart[i];
  float tot = block_reduce(v, red, 4);
  if (threadIdx.x == 0) out[0] = tot;
}

extern "C" void kernel_launch(void* const* d_in, const int* in_sizes, int n_in,
                              void* d_out, int out_size, void* d_ws, size_t ws_size,
                              hipStream_t stream) {
  const float* x = (const float*)d_in[0];
  char* ws = (char*)d_ws;
  unsigned short* RT  = (unsigned short*)(ws + OFF_RT);
  float* xm           = (float*)(ws + OFF_XM);
  float* m            = (float*)(ws + OFF_M);
  unsigned short* rmT = (unsigned short*)(ws + OFF_RM);
  float* P1           = (float*)(ws + OFF_P1);
  float* P2           = (float*)(ws + OFF_P2);
  float* norms        = (float*)(ws + OFF_NORMS);
  float* bpart        = (float*)(ws + OFF_BPART);
  float* out          = (float*)d_out;

  hipLaunchKernelGGL(k1_means_convert, dim3(6144), dim3(256), 0, stream, x, xm, RT);
  hipLaunchKernelGGL(k2_slice_mean, dim3(2), dim3(768), 0, stream, xm, m, rmT);
  // big GEMM: 21 triangle tiles x 2 slices x ksplit 6 = 252 blocks, K=16384 (256 BK-steps)
  hipLaunchKernelGGL(gemm_ata, dim3(252), dim3(256), 0, stream,
                     RT, (size_t)(768ull * 16384ull), 16384, P1, 6, 256);
  // between GEMM: K=128 (2 BK-steps), 42 blocks
  hipLaunchKernelGGL(gemm_ata, dim3(42), dim3(256), 0, stream,
                     rmT, (size_t)(768ull * 128ull), 128, P2, 1, 2);
  hipLaunchKernelGGL(k4_norms, dim3(1), dim3(768), 0, stream, P1, P2, m, norms);
  hipLaunchKernelGGL(k5_elem, dim3(1344), dim3(256), 0, stream, P1, P2, m, norms, bpart);
  hipLaunchKernelGGL(k6_final, dim3(1), dim3(256), 0, stream, bpart, out);
}

// Round 7
// 122.005 us; speedup vs baseline: 1.4479x; 1.3257x over previous
//
#include <hip/hip_runtime.h>

// Loss = ||corr_norm(within1)-corr_norm(within2)||^2 + ||corr_norm(between1)-corr_norm(between2)||^2
// within_s  ∝ G1_s - 128*P2_s - 16384*m_s m_s^T   (G1 = X^T X over slice, bf16 MFMA, K=16384)
// between_s ∝ P2_s = rm^T rm (rm = xm - m, K=128)
// corr_norm is scale-invariant -> no 1/16384 anywhere.

typedef float f32x2 __attribute__((ext_vector_type(2)));
typedef float f32x4 __attribute__((ext_vector_type(4)));
typedef short bf16x8 __attribute__((ext_vector_type(8)));

// ---- ws layout (bytes) ----
static constexpr size_t OFF_RT    = 0;                         // bf16 R_T [2][768][16384]  = 50,331,648
static constexpr size_t OFF_XM    = 50331648;                  // f32 xm [2][128][768]      = 786,432
static constexpr size_t OFF_M     = 51118080;                  // f32 m  [2][768]           = 6,144
static constexpr size_t OFF_RM    = 51124224;                  // bf16 rm_T [2][768][128]   = 393,216
static constexpr size_t OFF_P1    = 51517440;                  // f32 [252][128*128]        = 16,515,072
static constexpr size_t OFF_P2    = 68032512;                  // f32 [42][128*128]         = 2,752,512
static constexpr size_t OFF_NORMS = 70785024;                  // f32 [4]
static constexpr size_t OFF_BPART = 70785280;                  // f32 [1344]

__device__ __forceinline__ unsigned int f2bf_u32(float f) {
  union { float f; unsigned int u; } v; v.f = f;
  unsigned int u = v.u;
  unsigned int lsb = (u >> 16) & 1u;
  u += 0x7fffu + lsb;
  return u >> 16;
}

__device__ __forceinline__ void gload_lds16(const void* g, void* l) {
  __builtin_amdgcn_global_load_lds(
      (const __attribute__((address_space(1))) unsigned int*)g,
      (__attribute__((address_space(3))) unsigned int*)l, 16, 0, 0);
}

// ---------------- K1 v3: LDS-staged transpose-convert + column means ----------------
// grid 1536 = 256 borig x 6 dtiles(128); block 256 = 4 waves; LDS f32 [128][129] = 66KB.
// Phase 1: wave reads contiguous 512B row-segments (64 lanes x f32x2) -> LDS (pad 129).
// Phase 2: column reads from LDS (4-way bank, 1.58x), bf16-pack, store two contiguous
// 256B d-row segments per wave instr. Column mean via 32-lane shfl reduce.
__global__ void __launch_bounds__(256) k1_means_convert(const float* __restrict__ x,
                                                        float* __restrict__ xm,
                                                        unsigned short* __restrict__ RT) {
  __shared__ float T[128][129];
  int bid = blockIdx.x;
  int dt = bid % 6, borig = bid / 6;
  int s = borig & 1, b = borig >> 1;
  int tid = threadIdx.x, w = tid >> 6, lane = tid & 63;

  // ---- phase 1: global -> LDS (coalesced 512B per wave instr) ----
  const float* xb = x + (size_t)borig * (128 * 768) + dt * 128 + 2 * lane;
#pragma unroll 4
  for (int i = 0; i < 32; ++i) {
    int n = w * 32 + i;
    f32x2 v = *reinterpret_cast<const f32x2*>(xb + (size_t)n * 768);
    *reinterpret_cast<f32x2*>(&T[n][2 * lane]) = v;
  }
  __syncthreads();

  // ---- phase 2: LDS columns -> bf16 RT rows + means ----
  int half = lane >> 5;
  int nb = (lane & 31) * 4;
  unsigned short* rtbase = RT + (size_t)s * (768ull * 16384ull) + (size_t)(b * 128 + nb);
  float* xmbase = xm + ((size_t)(s * 128 + b)) * 768ull;
#pragma unroll 2
  for (int i = 0; i < 16; ++i) {
    int d_loc = w * 32 + 2 * i + half;
    float f0 = T[nb + 0][d_loc];
    float f1 = T[nb + 1][d_loc];
    float f2 = T[nb + 2][d_loc];
    float f3 = T[nb + 3][d_loc];
    uint2 st;
    st.x = f2bf_u32(f0) | (f2bf_u32(f1) << 16);
    st.y = f2bf_u32(f2) | (f2bf_u32(f3) << 16);
    *reinterpret_cast<uint2*>(rtbase + (size_t)(dt * 128 + d_loc) * 16384ull) = st;
    float cs = f0 + f1 + f2 + f3;
#pragma unroll
    for (int off = 16; off; off >>= 1) cs += __shfl_xor(cs, off, 64);
    if ((lane & 31) == 0) xmbase[dt * 128 + d_loc] = cs * (1.f / 128.f);
  }
}

// ---------------- K2 v2: slice mean + bf16 residual-mean transpose (parallel) ----------------
// grid 24 = 2 slices x 12 dgroups(64); block 256. Coalesced 256B xm reads.
__global__ void __launch_bounds__(256) k2_slice_mean(const float* __restrict__ xm,
                                                     float* __restrict__ m,
                                                     unsigned short* __restrict__ rmT) {
  __shared__ float pm[4][64];
  __shared__ float ml[64];
  int s = blockIdx.x / 12, dg = blockIdx.x % 12;
  int t = threadIdx.x;
  int d_loc = t & 63, part = t >> 6;
  int d = dg * 64 + d_loc;
  const float* base = xm + (size_t)s * 128ull * 768ull + d;
  float acc = 0.f;
#pragma unroll 4
  for (int i = 0; i < 32; ++i) acc += base[(size_t)(part * 32 + i) * 768ull];
  pm[part][d_loc] = acc;
  __syncthreads();
  if (t < 64) {
    float mv = (pm[0][t] + pm[1][t] + pm[2][t] + pm[3][t]) * (1.f / 128.f);
    m[s * 768 + dg * 64 + t] = mv;
    ml[t] = mv;
  }
  __syncthreads();
  float mv = ml[d_loc];
  unsigned short* rt = rmT + ((size_t)s * 768ull + d) * 128ull + part * 32;
#pragma unroll 4
  for (int i = 0; i < 32; ++i)
    rt[i] = (unsigned short)f2bf_u32(base[(size_t)(part * 32 + i) * 768ull] - mv);
}

// ---------------- K3: C = A^T A tile GEMM (bf16 MFMA), triangle tiles, split-K ----------------
__device__ __forceinline__ void stage_tile(const unsigned short* __restrict__ g, int KP, int k0,
                                           unsigned short* lds, int wave, int lane) {
#pragma unroll
  for (int i = 0; i < 4; ++i) {
    int cb = (i * 4 + wave) * 64;       // wave-uniform chunk base
    int chunk = cb + lane;
    int r = chunk >> 3, sl = chunk & 7;
    int ss = sl ^ (r & 7);              // inverse-swizzled global source
    const unsigned short* src = g + (size_t)r * KP + (k0 + ss * 8);
    gload_lds16(src, lds + (size_t)cb * 8);
  }
}

__device__ __forceinline__ bf16x8 read_frag(const unsigned short* lds, int row, int slot) {
  int chunk = row * 8 + (slot ^ (row & 7));   // swizzled read
  return *reinterpret_cast<const bf16x8*>(lds + chunk * 8);
}

__device__ __forceinline__ void tp2tile(int tp, int& td, int& te) {
  td = 0; int t2 = tp;
  while (t2 >= 6 - td) { t2 -= 6 - td; ++td; }
  te = td + t2;
}

__global__ void __launch_bounds__(256) gemm_ata(const unsigned short* __restrict__ R,
                                                size_t slice_stride, int KP,
                                                float* __restrict__ P, int ksplit, int tot_steps) {
  __shared__ unsigned short Ta[128 * 64];
  __shared__ unsigned short Tb[128 * 64];
  int bid = blockIdx.x;
  int c = bid % ksplit; int rest = bid / ksplit;
  int s = rest & 1; int tp = rest >> 1;
  int td, te; tp2tile(tp, td, te);
  int step0 = (tot_steps * c) / ksplit, step1 = (tot_steps * (c + 1)) / ksplit;
  const unsigned short* Ra = R + (size_t)s * slice_stride + (size_t)(td * 128) * KP;
  const unsigned short* Rb = R + (size_t)s * slice_stride + (size_t)(te * 128) * KP;
  int tid = threadIdx.x, wave = tid >> 6, lane = tid & 63;
  int m_off = (wave >> 1) * 64, n_off = (wave & 1) * 64;
  int row_a = m_off + (lane & 15), row_b = n_off + (lane & 15);
  f32x4 acc[4][4];
#pragma unroll
  for (int i = 0; i < 4; ++i)
#pragma unroll
    for (int j = 0; j < 4; ++j) { acc[i][j][0]=0.f; acc[i][j][1]=0.f; acc[i][j][2]=0.f; acc[i][j][3]=0.f; }

  for (int kt = step0; kt < step1; ++kt) {
    int k0 = kt * 64;
    __syncthreads();
    stage_tile(Ra, KP, k0, Ta, wave, lane);
    stage_tile(Rb, KP, k0, Tb, wave, lane);
    __syncthreads();
#pragma unroll
    for (int ks = 0; ks < 2; ++ks) {
      bf16x8 a[4], b[4];
      int slot = ks * 4 + (lane >> 4);
#pragma unroll
      for (int mi = 0; mi < 4; ++mi) a[mi] = read_frag(Ta, row_a + mi * 16, slot);
#pragma unroll
      for (int ni = 0; ni < 4; ++ni) b[ni] = read_frag(Tb, row_b + ni * 16, slot);
#pragma unroll
      for (int mi = 0; mi < 4; ++mi)
#pragma unroll
        for (int ni = 0; ni < 4; ++ni)
          acc[mi][ni] = __builtin_amdgcn_mfma_f32_16x16x32_bf16(a[mi], b[ni], acc[mi][ni], 0, 0, 0);
    }
  }
  float* pout = P + (size_t)bid * (128 * 128);
  int hi = lane >> 4, lo = lane & 15;
#pragma unroll
  for (int mi = 0; mi < 4; ++mi)
#pragma unroll
    for (int ni = 0; ni < 4; ++ni)
#pragma unroll
      for (int r = 0; r < 4; ++r) {
        int rr = m_off + mi * 16 + hi * 4 + r;
        int cc = n_off + ni * 16 + lo;
        pout[rr * 128 + cc] = acc[mi][ni][r];
      }
}

// ---------------- reduction helper ----------------
__device__ __forceinline__ float block_reduce(float v, float* lds, int nwaves) {
  int lane = threadIdx.x & 63, w = threadIdx.x >> 6;
#pragma unroll
  for (int off = 32; off; off >>= 1) v += __shfl_down(v, off, 64);
  if (lane == 0) lds[w] = v;
  __syncthreads();
  float r = 0.f;
  if (threadIdx.x == 0) for (int i = 0; i < nwaves; ++i) r += lds[i];
  __syncthreads();
  return r;  // valid on thread 0
}

// ---------------- K4: diag norms ----------------
__global__ void k4_norms(const float* __restrict__ P1, const float* __restrict__ P2,
                         const float* __restrict__ m, float* __restrict__ norms) {
  __shared__ float red[12];
  int d = threadIdx.x;  // 768
  int td = d >> 7, r = d & 127;
  int tpd = td * 6 - (td * (td - 1)) / 2;   // diagonal tile index
  float vals[4];
  for (int s = 0; s < 2; ++s) {
    float g1 = 0.f;
    const float* b1 = P1 + (size_t)((tpd * 2 + s) * 6) * 16384ull + r * 129;
    for (int c6 = 0; c6 < 6; ++c6) g1 += b1[(size_t)c6 * 16384ull];
    float p2v = P2[(size_t)(tpd * 2 + s) * 16384ull + r * 129];
    float mv = m[s * 768 + d];
    float wd = g1 - 128.0f * p2v - 16384.0f * mv * mv;
    vals[0 + s] = wd * wd;
    vals[2 + s] = p2v * p2v;
  }
  for (int i = 0; i < 4; ++i) {
    float tot = block_reduce(vals[i], red, 12);
    if (threadIdx.x == 0) norms[i] = sqrtf(tot);
    __syncthreads();
  }
}

// ---------------- K5: elementwise squared diffs (triangle-weighted) ----------------
__global__ void k5_elem(const float* __restrict__ P1, const float* __restrict__ P2,
                        const float* __restrict__ m, const float* __restrict__ norms,
                        float* __restrict__ bpart) {
  __shared__ float red[4];
  int bid = blockIdx.x;
  int tp = bid >> 6;
  int td, te; tp2tile(tp, td, te);
  int idx = ((bid & 63) << 8) + threadIdx.x;  // 0..16383 within tile
  int r = idx >> 7, cc = idx & 127;
  int d = td * 128 + r, e = te * 128 + cc;
  float w[2], bt[2];
  for (int s = 0; s < 2; ++s) {
    const float* base1 = P1 + (size_t)((tp * 2 + s) * 6) * 16384ull + idx;
    float g1 = 0.f;
    for (int c6 = 0; c6 < 6; ++c6) g1 += base1[(size_t)c6 * 16384ull];
    float p2v = P2[(size_t)(tp * 2 + s) * 16384ull + idx];
    float W = g1 - 128.0f * p2v - 16384.0f * m[s * 768 + d] * m[s * 768 + e];
    w[s] = W / norms[s];
    bt[s] = p2v / norms[2 + s];
  }
  float dw = w[0] - w[1], db = bt[0] - bt[1];
  float contrib = dw * dw + db * db;
  if (td != te) contrib *= 2.0f;
  float tot = block_reduce(contrib, red, 4);
  if (threadIdx.x == 0) bpart[bid] = tot;
}

// ---------------- K6: final sum ----------------
__global__ void k6_final(const float* __restrict__ bpart, float* __restrict__ out) {
  __shared__ float red[4];
  float v = 0.f;
  for (int i = threadIdx.x; i < 1344; i += 256) v += bpart[i];
  float tot = block_reduce(v, red, 4);
  if (threadIdx.x == 0) out[0] = tot;
}

extern "C" void kernel_launch(void* const* d_in, const int* in_sizes, int n_in,
                              void* d_out, int out_size, void* d_ws, size_t ws_size,
                              hipStream_t stream) {
  const float* x = (const float*)d_in[0];
  char* ws = (char*)d_ws;
  unsigned short* RT  = (unsigned short*)(ws + OFF_RT);
  float* xm           = (float*)(ws + OFF_XM);
  float* m            = (float*)(ws + OFF_M);
  unsigned short* rmT = (unsigned short*)(ws + OFF_RM);
  float* P1           = (float*)(ws + OFF_P1);
  float* P2           = (float*)(ws + OFF_P2);
  float* norms        = (float*)(ws + OFF_NORMS);
  float* bpart        = (float*)(ws + OFF_BPART);
  float* out          = (float*)d_out;

  hipLaunchKernelGGL(k1_means_convert, dim3(1536), dim3(256), 0, stream, x, xm, RT);
  hipLaunchKernelGGL(k2_slice_mean, dim3(24), dim3(256), 0, stream, xm, m, rmT);
  // big GEMM: 21 triangle tiles x 2 slices x ksplit 6 = 252 blocks, K=16384 (256 BK-steps)
  hipLaunchKernelGGL(gemm_ata, dim3(252), dim3(256), 0, stream,
                     RT, (size_t)(768ull * 16384ull), 16384, P1, 6, 256);
  // between GEMM: K=128 (2 BK-steps), 42 blocks
  hipLaunchKernelGGL(gemm_ata, dim3(42), dim3(256), 0, stream,
                     rmT, (size_t)(768ull * 128ull), 128, P2, 1, 2);
  hipLaunchKernelGGL(k4_norms, dim3(1), dim3(768), 0, stream, P1, P2, m, norms);
  hipLaunchKernelGGL(k5_elem, dim3(1344), dim3(256), 0, stream, P1, P2, m, norms, bpart);
  hipLaunchKernelGGL(k6_final, dim3(1), dim3(256), 0, stream, bpart, out);
}

// Round 8
// 103.402 us; speedup vs baseline: 1.7084x; 1.1799x over previous
//
#include <hip/hip_runtime.h>

// Loss = ||corr_norm(within1)-corr_norm(within2)||^2 + ||corr_norm(between1)-corr_norm(between2)||^2
// within_s  ∝ G1_s - 128*P2_s - 16384*m_s m_s^T   (G1 = X^T X over slice, bf16 MFMA, K=16384)
// between_s ∝ P2_s = rm^T rm (rm = xm - m, K=128)
// corr_norm is scale-invariant -> no 1/16384 anywhere.

typedef float f32x2 __attribute__((ext_vector_type(2)));
typedef float f32x4 __attribute__((ext_vector_type(4)));
typedef short bf16x8 __attribute__((ext_vector_type(8)));
typedef unsigned short u16x4 __attribute__((ext_vector_type(4)));

// ---- ws layout (bytes); P1 last so split-K partial count adapts to ws_size ----
static constexpr size_t OFF_RT    = 0;                         // bf16 R_T [2][768][16384]  = 50,331,648
static constexpr size_t OFF_XM    = 50331648;                  // f32 xm [2][128][768]      = 786,432
static constexpr size_t OFF_M     = 51118080;                  // f32 m  [2][768]           = 6,144
static constexpr size_t OFF_RM    = 51124224;                  // bf16 rm_T [2][768][128]   = 393,216
static constexpr size_t OFF_P2    = 51517440;                  // f32 [42][128*128]         = 2,752,512
static constexpr size_t OFF_NORMS = 54269952;                  // f32 [4] (pad 256)
static constexpr size_t OFF_BPART = 54270208;                  // f32 [1344] (pad 8192)
static constexpr size_t OFF_P1    = 54278400;                  // f32 [42*ksplit][128*128]

__device__ __forceinline__ unsigned int f2bf_u32(float f) {
  union { float f; unsigned int u; } v; v.f = f;
  unsigned int u = v.u;
  unsigned int lsb = (u >> 16) & 1u;
  u += 0x7fffu + lsb;
  return u >> 16;
}

__device__ __forceinline__ void gload_lds16(const void* g, void* l) {
  __builtin_amdgcn_global_load_lds(
      (const __attribute__((address_space(1))) unsigned int*)g,
      (__attribute__((address_space(3))) unsigned int*)l, 16, 0, 0);
}

// ---------------- K1 v4: bf16-in-LDS transpose-convert + f32 register means ----------------
// grid 1536 = 256 borig x 6 dtiles(128); block 256 = 4 waves.
// LDS: T ushort[128 d][132] (35KB total w/ pm -> 4 blocks/CU).
// Phase 1: lane reads f32x2 (d=2l,2l+1) for 32 n's (coalesced 512B/instr),
//   accumulates f32 colsums, packs bf16 x4 along n, ds_write_b64 transposed.
// Means: pm[4][128] partials, one barrier, threads 0-127 finish + store xm.
// Phase 2: ds_read_b64 row segment (already bf16, n-order) -> 8B global store;
//   per wave instr: two 256B contiguous RT segments. No bpermutes anywhere.
__global__ void __launch_bounds__(256) k1_means_convert(const float* __restrict__ x,
                                                        float* __restrict__ xm,
                                                        unsigned short* __restrict__ RT) {
  __shared__ unsigned short T[128][132];
  __shared__ float pm[4][128];
  int bid = blockIdx.x;
  int dt = bid % 6, borig = bid / 6;
  int s = borig & 1, b = borig >> 1;
  int tid = threadIdx.x, w = tid >> 6, lane = tid & 63;

  const float* xb = x + (size_t)borig * (128 * 768) + dt * 128 + 2 * lane;
  float cs0 = 0.f, cs1 = 0.f;
#pragma unroll
  for (int g = 0; g < 8; ++g) {
    int n0 = w * 32 + g * 4;
    f32x2 a0 = *reinterpret_cast<const f32x2*>(xb + (size_t)(n0 + 0) * 768);
    f32x2 a1 = *reinterpret_cast<const f32x2*>(xb + (size_t)(n0 + 1) * 768);
    f32x2 a2 = *reinterpret_cast<const f32x2*>(xb + (size_t)(n0 + 2) * 768);
    f32x2 a3 = *reinterpret_cast<const f32x2*>(xb + (size_t)(n0 + 3) * 768);
    cs0 += a0[0] + a1[0] + a2[0] + a3[0];
    cs1 += a0[1] + a1[1] + a2[1] + a3[1];
    u16x4 p0, p1;
    p0[0] = (unsigned short)f2bf_u32(a0[0]); p0[1] = (unsigned short)f2bf_u32(a1[0]);
    p0[2] = (unsigned short)f2bf_u32(a2[0]); p0[3] = (unsigned short)f2bf_u32(a3[0]);
    p1[0] = (unsigned short)f2bf_u32(a0[1]); p1[1] = (unsigned short)f2bf_u32(a1[1]);
    p1[2] = (unsigned short)f2bf_u32(a2[1]); p1[3] = (unsigned short)f2bf_u32(a3[1]);
    *reinterpret_cast<u16x4*>(&T[2 * lane + 0][n0]) = p0;
    *reinterpret_cast<u16x4*>(&T[2 * lane + 1][n0]) = p1;
  }
  *reinterpret_cast<f32x2*>(&pm[w][2 * lane]) = f32x2{cs0, cs1};
  __syncthreads();

  if (tid < 128) {
    float mv = (pm[0][tid] + pm[1][tid] + pm[2][tid] + pm[3][tid]) * (1.f / 128.f);
    xm[((size_t)(s * 128 + b)) * 768ull + dt * 128 + tid] = mv;
  }

  int half = lane >> 5;
  int nb = (lane & 31) * 4;
  unsigned short* rtbase = RT + (size_t)s * (768ull * 16384ull) + (size_t)(b * 128 + nb);
#pragma unroll
  for (int i = 0; i < 16; ++i) {
    int d_loc = w * 32 + 2 * i + half;
    uint2 v = *reinterpret_cast<const uint2*>(&T[d_loc][nb]);
    *reinterpret_cast<uint2*>(rtbase + (size_t)(dt * 128 + d_loc) * 16384ull) = v;
  }
}

// ---------------- K2 v2: slice mean + bf16 residual-mean transpose (parallel) ----------------
// grid 24 = 2 slices x 12 dgroups(64); block 256. Coalesced 256B xm reads.
__global__ void __launch_bounds__(256) k2_slice_mean(const float* __restrict__ xm,
                                                     float* __restrict__ m,
                                                     unsigned short* __restrict__ rmT) {
  __shared__ float pm[4][64];
  __shared__ float ml[64];
  int s = blockIdx.x / 12, dg = blockIdx.x % 12;
  int t = threadIdx.x;
  int d_loc = t & 63, part = t >> 6;
  int d = dg * 64 + d_loc;
  const float* base = xm + (size_t)s * 128ull * 768ull + d;
  float acc = 0.f;
#pragma unroll 4
  for (int i = 0; i < 32; ++i) acc += base[(size_t)(part * 32 + i) * 768ull];
  pm[part][d_loc] = acc;
  __syncthreads();
  if (t < 64) {
    float mv = (pm[0][t] + pm[1][t] + pm[2][t] + pm[3][t]) * (1.f / 128.f);
    m[s * 768 + dg * 64 + t] = mv;
    ml[t] = mv;
  }
  __syncthreads();
  float mv = ml[d_loc];
  unsigned short* rt = rmT + ((size_t)s * 768ull + d) * 128ull + part * 32;
#pragma unroll 4
  for (int i = 0; i < 32; ++i)
    rt[i] = (unsigned short)f2bf_u32(base[(size_t)(part * 32 + i) * 768ull] - mv);
}

// ---------------- K3: C = A^T A tile GEMM (bf16 MFMA), triangle tiles, split-K, dbuf ----------------
__device__ __forceinline__ void stage_tile(const unsigned short* __restrict__ g, int KP, int k0,
                                           unsigned short* lds, int wave, int lane) {
#pragma unroll
  for (int i = 0; i < 4; ++i) {
    int cb = (i * 4 + wave) * 64;       // wave-uniform chunk base
    int chunk = cb + lane;
    int r = chunk >> 3, sl = chunk & 7;
    int ss = sl ^ (r & 7);              // inverse-swizzled global source
    const unsigned short* src = g + (size_t)r * KP + (k0 + ss * 8);
    gload_lds16(src, lds + (size_t)cb * 8);
  }
}

__device__ __forceinline__ bf16x8 read_frag(const unsigned short* lds, int row, int slot) {
  int chunk = row * 8 + (slot ^ (row & 7));   // swizzled read
  return *reinterpret_cast<const bf16x8*>(lds + chunk * 8);
}

__device__ __forceinline__ void tp2tile(int tp, int& td, int& te) {
  td = 0; int t2 = tp;
  while (t2 >= 6 - td) { t2 -= 6 - td; ++td; }
  te = td + t2;
}

__global__ void __launch_bounds__(256) gemm_ata(const unsigned short* __restrict__ R,
                                                size_t slice_stride, int KP,
                                                float* __restrict__ P, int ksplit, int tot_steps) {
  __shared__ unsigned short Ta[2][128 * 64];
  __shared__ unsigned short Tb[2][128 * 64];
  int bid = blockIdx.x;
  int c = bid % ksplit; int rest = bid / ksplit;
  int s = rest & 1; int tp = rest >> 1;
  int td, te; tp2tile(tp, td, te);
  int step0 = (tot_steps * c) / ksplit, step1 = (tot_steps * (c + 1)) / ksplit;
  const unsigned short* Ra = R + (size_t)s * slice_stride + (size_t)(td * 128) * KP;
  const unsigned short* Rb = R + (size_t)s * slice_stride + (size_t)(te * 128) * KP;
  int tid = threadIdx.x, wave = tid >> 6, lane = tid & 63;
  int m_off = (wave >> 1) * 64, n_off = (wave & 1) * 64;
  int row_a = m_off + (lane & 15), row_b = n_off + (lane & 15);
  f32x4 acc[4][4];
#pragma unroll
  for (int i = 0; i < 4; ++i)
#pragma unroll
    for (int j = 0; j < 4; ++j) { acc[i][j][0]=0.f; acc[i][j][1]=0.f; acc[i][j][2]=0.f; acc[i][j][3]=0.f; }

  // prologue: stage first tile
  stage_tile(Ra, KP, step0 * 64, Ta[0], wave, lane);
  stage_tile(Rb, KP, step0 * 64, Tb[0], wave, lane);
  __syncthreads();

  int cur = 0;
  for (int kt = step0; kt < step1; ++kt) {
    // prefetch next tile into the other buffer (overlaps with MFMA below)
    if (kt + 1 < step1) {
      stage_tile(Ra, KP, (kt + 1) * 64, Ta[cur ^ 1], wave, lane);
      stage_tile(Rb, KP, (kt + 1) * 64, Tb[cur ^ 1], wave, lane);
    }
#pragma unroll
    for (int ks = 0; ks < 2; ++ks) {
      bf16x8 a[4], b[4];
      int slot = ks * 4 + (lane >> 4);
#pragma unroll
      for (int mi = 0; mi < 4; ++mi) a[mi] = read_frag(Ta[cur], row_a + mi * 16, slot);
#pragma unroll
      for (int ni = 0; ni < 4; ++ni) b[ni] = read_frag(Tb[cur], row_b + ni * 16, slot);
#pragma unroll
      for (int mi = 0; mi < 4; ++mi)
#pragma unroll
        for (int ni = 0; ni < 4; ++ni)
          acc[mi][ni] = __builtin_amdgcn_mfma_f32_16x16x32_bf16(a[mi], b[ni], acc[mi][ni], 0, 0, 0);
    }
    __syncthreads();   // drains vmcnt (staged tile ready) + all reads of buf[cur] done
    cur ^= 1;
  }
  float* pout = P + (size_t)bid * (128 * 128);
  int hi = lane >> 4, lo = lane & 15;
#pragma unroll
  for (int mi = 0; mi < 4; ++mi)
#pragma unroll
    for (int ni = 0; ni < 4; ++ni)
#pragma unroll
      for (int r = 0; r < 4; ++r) {
        int rr = m_off + mi * 16 + hi * 4 + r;
        int cc = n_off + ni * 16 + lo;
        pout[rr * 128 + cc] = acc[mi][ni][r];
      }
}

// ---------------- reduction helper ----------------
__device__ __forceinline__ float block_reduce(float v, float* lds, int nwaves) {
  int lane = threadIdx.x & 63, w = threadIdx.x >> 6;
#pragma unroll
  for (int off = 32; off; off >>= 1) v += __shfl_down(v, off, 64);
  if (lane == 0) lds[w] = v;
  __syncthreads();
  float r = 0.f;
  if (threadIdx.x == 0) for (int i = 0; i < nwaves; ++i) r += lds[i];
  __syncthreads();
  return r;  // valid on thread 0
}

// ---------------- K4: diag norms ----------------
__global__ void k4_norms(const float* __restrict__ P1, const float* __restrict__ P2,
                         const float* __restrict__ m, float* __restrict__ norms, int ksplit) {
  __shared__ float red[12];
  int d = threadIdx.x;  // 768
  int td = d >> 7, r = d & 127;
  int tpd = td * 6 - (td * (td - 1)) / 2;   // diagonal tile index
  float vals[4];
  for (int s = 0; s < 2; ++s) {
    float g1 = 0.f;
    const float* b1 = P1 + (size_t)((tpd * 2 + s) * ksplit) * 16384ull + r * 129;
    for (int c6 = 0; c6 < ksplit; ++c6) g1 += b1[(size_t)c6 * 16384ull];
    float p2v = P2[(size_t)(tpd * 2 + s) * 16384ull + r * 129];
    float mv = m[s * 768 + d];
    float wd = g1 - 128.0f * p2v - 16384.0f * mv * mv;
    vals[0 + s] = wd * wd;
    vals[2 + s] = p2v * p2v;
  }
  for (int i = 0; i < 4; ++i) {
    float tot = block_reduce(vals[i], red, 12);
    if (threadIdx.x == 0) norms[i] = sqrtf(tot);
    __syncthreads();
  }
}

// ---------------- K5: elementwise squared diffs (triangle-weighted) ----------------
__global__ void k5_elem(const float* __restrict__ P1, const float* __restrict__ P2,
                        const float* __restrict__ m, const float* __restrict__ norms,
                        float* __restrict__ bpart, int ksplit) {
  __shared__ float red[4];
  int bid = blockIdx.x;
  int tp = bid >> 6;
  int td, te; tp2tile(tp, td, te);
  int idx = ((bid & 63) << 8) + threadIdx.x;  // 0..16383 within tile
  int r = idx >> 7, cc = idx & 127;
  int d = td * 128 + r, e = te * 128 + cc;
  float w[2], bt[2];
  for (int s = 0; s < 2; ++s) {
    const float* base1 = P1 + (size_t)((tp * 2 + s) * ksplit) * 16384ull + idx;
    float g1 = 0.f;
    for (int c6 = 0; c6 < ksplit; ++c6) g1 += base1[(size_t)c6 * 16384ull];
    float p2v = P2[(size_t)(tp * 2 + s) * 16384ull + idx];
    float W = g1 - 128.0f * p2v - 16384.0f * m[s * 768 + d] * m[s * 768 + e];
    w[s] = W / norms[s];
    bt[s] = p2v / norms[2 + s];
  }
  float dw = w[0] - w[1], db = bt[0] - bt[1];
  float contrib = dw * dw + db * db;
  if (td != te) contrib *= 2.0f;
  float tot = block_reduce(contrib, red, 4);
  if (threadIdx.x == 0) bpart[bid] = tot;
}

// ---------------- K6: final sum ----------------
__global__ void k6_final(const float* __restrict__ bpart, float* __restrict__ out) {
  __shared__ float red[4];
  float v = 0.f;
  for (int i = threadIdx.x; i < 1344; i += 256) v += bpart[i];
  float tot = block_reduce(v, red, 4);
  if (threadIdx.x == 0) out[0] = tot;
}

extern "C" void kernel_launch(void* const* d_in, const int* in_sizes, int n_in,
                              void* d_out, int out_size, void* d_ws, size_t ws_size,
                              hipStream_t stream) {
  const float* x = (const float*)d_in[0];
  char* ws = (char*)d_ws;
  unsigned short* RT  = (unsigned short*)(ws + OFF_RT);
  float* xm           = (float*)(ws + OFF_XM);
  float* m            = (float*)(ws + OFF_M);
  unsigned short* rmT = (unsigned short*)(ws + OFF_RM);
  float* P2           = (float*)(ws + OFF_P2);
  float* norms        = (float*)(ws + OFF_NORMS);
  float* bpart        = (float*)(ws + OFF_BPART);
  float* P1           = (float*)(ws + OFF_P1);
  float* out          = (float*)d_out;

  // adaptive split-K: fit P1 partials (42 tiles x ksplit x 64KB) in remaining ws
  size_t availP1 = (ws_size > OFF_P1) ? (ws_size - OFF_P1) : 0;
  int ksplit = (int)(availP1 / (42ull * 128 * 128 * 4));
  if (ksplit > 12) ksplit = 12;
  if (ksplit < 1) ksplit = 1;

  hipLaunchKernelGGL(k1_means_convert, dim3(1536), dim3(256), 0, stream, x, xm, RT);
  hipLaunchKernelGGL(k2_slice_mean, dim3(24), dim3(256), 0, stream, xm, m, rmT);
  // big GEMM: 21 triangle tiles x 2 slices x ksplit blocks, K=16384 (256 BK-steps)
  hipLaunchKernelGGL(gemm_ata, dim3(42 * ksplit), dim3(256), 0, stream,
                     RT, (size_t)(768ull * 16384ull), 16384, P1, ksplit, 256);
  // between GEMM: K=128 (2 BK-steps), 42 blocks
  hipLaunchKernelGGL(gemm_ata, dim3(42), dim3(256), 0, stream,
                     rmT, (size_t)(768ull * 128ull), 128, P2, 1, 2);
  hipLaunchKernelGGL(k4_norms, dim3(1), dim3(768), 0, stream, P1, P2, m, norms, ksplit);
  hipLaunchKernelGGL(k5_elem, dim3(1344), dim3(256), 0, stream, P1, P2, m, norms, bpart, ksplit);
  hipLaunchKernelGGL(k6_final, dim3(1), dim3(256), 0, stream, bpart, out);
}